// Round 7
// baseline (394.171 us; speedup 1.0000x reference)
//
#include <hip/hip_runtime.h>

#define PRIOR_SCALE 0.3f
#define NEGF (-1e30f)
#define LOG2E_F 1.4426950408889634f
#define LN2_F 0.6931471805599453f
#define K_SS 16   // time steps per superstep (one barrier per K_SS steps)

// Fused waitcnt+barrier: ONE asm block with "memory" clobber (round-5 lesson:
// s_barrier alone is not a compiler memory fence).
#define PHASE_BARRIER() \
  asm volatile("s_waitcnt lgkmcnt(0)\n\ts_barrier" ::: "memory")

__device__ __forceinline__ float fexp2(float x) { return __builtin_amdgcn_exp2f(x); }
__device__ __forceinline__ float flog2(float x) { return __builtin_amdgcn_logf(x); }

__device__ __forceinline__ float lse2b(float a, float b) {
  float m = fmaxf(a, b);
  float d = fminf(a, b) - m;
  return m + flog2(1.0f + fexp2(d));
}
// 3-term: max term's exp2 is exactly 1 -> 2 exp + 1 log
__device__ __forceinline__ float lse3b(float a, float b, float c) {
  float mx = fmaxf(fmaxf(a, b), c);                      // v_max3
  float mn = fminf(fminf(a, b), c);                      // v_min3
  float md = fmaxf(fminf(a, b), fminf(fmaxf(a, b), c));  // v_med3
  return mx + flog2(1.0f + fexp2(md - mx) + fexp2(mn - mx));
}

// lane-1 -> lane shift via DPP wave_shr:1 (pure VALU). Lane 0 receives `fill`.
__device__ __forceinline__ float shr1_dpp(float x, float fill) {
  return __int_as_float(__builtin_amdgcn_update_dpp(
      __float_as_int(fill), __float_as_int(x), 0x138 /*wave_shr:1*/, 0xF, 0xF, false));
}

// Un-sinkable prefetch: asm-pinned global_load_dword pair (label col + blank col).
__device__ __forceinline__ void issue_pair(float& e, float& b, uint32_t offE,
                                           uint32_t offB, uint64_t base) {
  asm volatile("global_load_dword %0, %2, %4\n\t"
               "global_load_dword %1, %3, %4"
               : "=v"(e), "=v"(b)
               : "v"(offE), "v"(offB), "s"(base));
}
// Counted wait tied to consumed values via data dependency (rule #18).
__device__ __forceinline__ void wait_pair(float& e, float& b) {
  asm volatile("s_waitcnt vmcnt(30)" : "+v"(e), "+v"(b));
}

// Blocks [0,N): CTC forward, 8 time-skewed waves, ONE position per lane
// (position j = threadIdx; thread 511 also owns position 512). Unified
// 3-term LSE; neighbor deps via two chained DPP shifts with mailbox fills.
// Blocks [N, N+pblocks): label-prior partial sums (2 t-stripes per block).
extern "C" __global__ void __launch_bounds__(512, 1)
ctc_fused_kernel(const float* __restrict__ lp, const float* __restrict__ lpri,
                 const int* __restrict__ tgt, const int* __restrict__ ilen,
                 const int* __restrict__ tlen, float* __restrict__ nll,
                 float* __restrict__ partial, int pblocks,
                 int T, int N, int V, int S) {
  if ((int)blockIdx.x >= N) {
    const int pb = blockIdx.x - N;
    const int v = threadIdx.x & 255;        // V == 256
    const int half = threadIdx.x >> 8;
    const int stripe = pb * 2 + half;
    const int nstripes = pblocks * 2;
    float s = 0.0f;
    for (int t = stripe; t < T; t += nstripes) {
      const float* base = lp + (size_t)t * N * V + v;
      for (int nn = 0; nn < N; ++nn) {
        float xv = base[(size_t)nn * V];
        s += (t < ilen[nn]) ? __expf(xv) : 0.0f;
      }
    }
    partial[(size_t)stripe * V + v] = s;
    return;
  }

  // ---------------- CTC forward path ------------------------------------
  const int n = blockIdx.x;
  const int g = threadIdx.x;               // position j = g (0..511)
  const int lane = g & 63;
  const int wid = __builtin_amdgcn_readfirstlane(threadIdx.x >> 6);  // 0..7
  __shared__ __align__(16) float mbr[7][64][2];  // [w][t&63][{A=lane63,B=lane62}]
  __shared__ float afin[513];

  const int len = __builtin_amdgcn_readfirstlane(ilen[n]);
  const int tl = tlen[n];

  const int* trow = tgt + n * S;
  const bool isl = (g & 1);                 // odd position = label s = g>>1
  const int sidx = g >> 1;
  const int tv = isl ? trow[sidx] : 0;      // emission column (0 for blanks)
  const float sk = (isl && sidx >= 1 && tv != trow[sidx - 1]) ? 0.0f : NEGF;
  const float epb = (-PRIOR_SCALE * lpri[0]) * LOG2E_F;
  const float ep  = isl ? ((-PRIOR_SCALE * lpri[tv]) * LOG2E_F) : epb;

  const float* rp = lp + (size_t)n * V;
  const uint32_t RBu = (uint32_t)(N * V * 4);   // row stride bytes
  const uint32_t cjb = (uint32_t)tv * 4u;
  const uint64_t gbase = (uint64_t)(uintptr_t)rp;

  // alpha init (t=0), base-2 domain
  float x = NEGF, x2 = NEGF;                // x = alpha[g]; x2 = alpha[512] (g==511)
  { float e0 = rp[tv];
    if (g <= 1) x = fmaf(e0, LOG2E_F, ep); }

  // mailbox ring init (covers the t=0 boundary and pre-skew slots)
  for (int idx = g; idx < 7 * 64 * 2; idx += 512) ((float*)mbr)[idx] = NEGF;

  // ---- emission ring: 16 named (label, blank) pairs, asm-pinned ----
  float eR0, eR1, eR2, eR3, eR4, eR5, eR6, eR7,
        eR8, eR9, eR10, eR11, eR12, eR13, eR14, eR15;
  float bR0, bR1, bR2, bR3, bR4, bR5, bR6, bR7,
        bR8, bR9, bR10, bR11, bR12, bR13, bR14, bR15;
#define PRO(K) { uint32_t tt = (uint32_t)((1 + K < len) ? (1 + K) : (len - 1)); \
                 issue_pair(eR##K, bR##K, tt * RBu + cjb, tt * RBu, gbase); }
  PRO(0) PRO(1) PRO(2) PRO(3) PRO(4) PRO(5) PRO(6) PRO(7)
  PRO(8) PRO(9) PRO(10) PRO(11) PRO(12) PRO(13) PRO(14) PRO(15)
#undef PRO
  uint32_t ofB;
  { uint32_t tn = (uint32_t)((1 + K_SS < len) ? (1 + K_SS) : (len - 1));
    ofB = tn * RBu; }

  // mailbox fill registers for the current superstep
  float fA0, fA1, fA2, fA3, fA4, fA5, fA6, fA7,
        fA8, fA9, fA10, fA11, fA12, fA13, fA14, fA15;
  float fB0, fB1, fB2, fB3, fB4, fB5, fB6, fB7,
        fB8, fB9, fB10, fB11, fB12, fB13, fB14, fB15;

  PHASE_BARRIER();  // mbr init visible

  const int nss = (len - 1 + K_SS - 1) / K_SS;
  const int P = nss + 7;     // 8 waves -> skew depth 7

#define STEP(KK, T_) {                                                         \
    const int t = (T_);                                                        \
    if (t < len) {                                                             \
      wait_pair(eR##KK, bR##KK);                                               \
      float e1  = fmaf(eR##KK, LOG2E_F, ep);                                   \
      float ebl = fmaf(bR##KK, LOG2E_F, epb);                                  \
      issue_pair(eR##KK, bR##KK, ofB + cjb, ofB, gbase);                       \
      ofB += ((t + 1 + K_SS) < len) ? RBu : 0u;                                \
      float am1 = shr1_dpp(x, fA##KK);                                         \
      float am2 = shr1_dpp(am1, fB##KK);                                       \
      float xold = x;                                                          \
      x = lse3b(x, am1, am2 + sk) + e1;                                        \
      if (g == 511) x2 = lse2b(x2, xold) + ebl;     /* position 512 */         \
      if (lane >= 62 && wid < 7) mbr[wid][t & 63][1 - (lane & 1)] = x;         \
    } }

  for (int p = 0; p < P; ++p) {
    const int i = p - wid;
    if (i >= 0 && i < nss) {
      const int t0 = 1 + i * K_SS;
      if (wid > 0) {
        // bulk mailbox read: writer x at t = t0-1 .. t0+14 (>=1 phase old)
        const float4* mq = (const float4*)&mbr[wid - 1][(i * K_SS) & 63][0];
        float4 q0 = mq[0], q1 = mq[1], q2 = mq[2], q3 = mq[3],
               q4 = mq[4], q5 = mq[5], q6 = mq[6], q7 = mq[7];
        fA0 = q0.x; fB0 = q0.y; fA1 = q0.z; fB1 = q0.w;
        fA2 = q1.x; fB2 = q1.y; fA3 = q1.z; fB3 = q1.w;
        fA4 = q2.x; fB4 = q2.y; fA5 = q2.z; fB5 = q2.w;
        fA6 = q3.x; fB6 = q3.y; fA7 = q3.z; fB7 = q3.w;
        fA8 = q4.x; fB8 = q4.y; fA9 = q4.z; fB9 = q4.w;
        fA10 = q5.x; fB10 = q5.y; fA11 = q5.z; fB11 = q5.w;
        fA12 = q6.x; fB12 = q6.y; fA13 = q6.z; fB13 = q6.w;
        fA14 = q7.x; fB14 = q7.y; fA15 = q7.z; fB15 = q7.w;
      } else {
        fA0 = fA1 = fA2 = fA3 = fA4 = fA5 = fA6 = fA7 = NEGF;
        fA8 = fA9 = fA10 = fA11 = fA12 = fA13 = fA14 = fA15 = NEGF;
        fB0 = fB1 = fB2 = fB3 = fB4 = fB5 = fB6 = fB7 = NEGF;
        fB8 = fB9 = fB10 = fB11 = fB12 = fB13 = fB14 = fB15 = NEGF;
      }
      STEP(0, t0 + 0)  STEP(1, t0 + 1)  STEP(2, t0 + 2)  STEP(3, t0 + 3)
      STEP(4, t0 + 4)  STEP(5, t0 + 5)  STEP(6, t0 + 6)  STEP(7, t0 + 7)
      STEP(8, t0 + 8)  STEP(9, t0 + 9)  STEP(10, t0 + 10) STEP(11, t0 + 11)
      STEP(12, t0 + 12) STEP(13, t0 + 13) STEP(14, t0 + 14) STEP(15, t0 + 15)
    }
    PHASE_BARRIER();
  }
#undef STEP

  // drain outstanding asm loads; keep dest regs live until drained
  asm volatile("s_waitcnt vmcnt(0)");
  asm volatile("" :: "v"(eR0), "v"(eR1), "v"(eR2), "v"(eR3), "v"(eR4),
                     "v"(eR5), "v"(eR6), "v"(eR7), "v"(eR8), "v"(eR9),
                     "v"(eR10), "v"(eR11), "v"(eR12), "v"(eR13), "v"(eR14), "v"(eR15));
  asm volatile("" :: "v"(bR0), "v"(bR1), "v"(bR2), "v"(bR3), "v"(bR4),
                     "v"(bR5), "v"(bR6), "v"(bR7), "v"(bR8), "v"(bR9),
                     "v"(bR10), "v"(bR11), "v"(bR12), "v"(bR13), "v"(bR14), "v"(bR15));

  afin[g] = x;
  if (g == 511) afin[512] = x2;
  __syncthreads();
  if (g == 0) {
    const int i1 = 2 * tl;
    float ll = lse2b(afin[i1], afin[i1 - 1]) * LN2_F;
    nll[n] = -ll / (float)tl;
  }
}

extern "C" __global__ void finalize_kernel(const float* __restrict__ partial, int nstripes,
                                           const float* __restrict__ nll,
                                           float* __restrict__ out, int N, int V) {
  const int v = threadIdx.x;  // 256 == V
  float s = 0.0f;
  for (int pb = 0; pb < nstripes; ++pb) s += partial[(size_t)pb * V + v];
  out[1 + v] = __logf(s);
  if (v == 0) {
    float acc = 0.0f;
#pragma unroll 8
    for (int i = 0; i < N; ++i) acc += nll[i];
    out[0] = acc / (float)N;
  }
}

extern "C" void kernel_launch(void* const* d_in, const int* in_sizes, int n_in,
                              void* d_out, int out_size, void* d_ws, size_t ws_size,
                              hipStream_t stream) {
  const float* lp   = (const float*)d_in[0];  // [T,N,V] fp32
  const float* lpri = (const float*)d_in[1];  // [1,V]   fp32
  const int*   tgt  = (const int*)d_in[2];    // [N,S]
  const int*   ilen = (const int*)d_in[3];    // [N]
  const int*   tlen = (const int*)d_in[4];    // [N]
  const int V = in_sizes[1];
  const int N = in_sizes[3];
  const int S = in_sizes[2] / N;
  const int T = in_sizes[0] / (N * V);

  int pblocks = 100;  // prior blocks (2 stripes each); 32 + 100 = 132 blocks
  size_t need = ((size_t)(2 * pblocks) * V + 64) * sizeof(float);
  if (ws_size < need) {
    long avail = (long)(ws_size / sizeof(float)) - 64;
    pblocks = (int)(avail / (2 * V));
    if (pblocks < 1) pblocks = 1;
  }
  const int nstripes = 2 * pblocks;

  float* out = (float*)d_out;                    // [0]=loss, [1..V]=prior logsumexp
  float* partial = (float*)d_ws;                 // [nstripes*V]
  float* nll = partial + (size_t)nstripes * V;   // [N]

  ctc_fused_kernel<<<N + pblocks, 512, 0, stream>>>(lp, lpri, tgt, ilen, tlen,
                                                    nll, partial, pblocks, T, N, V, S);
  finalize_kernel<<<1, 256, 0, stream>>>(partial, nstripes, nll, out, N, V);
}